// Round 2
// baseline (599.861 us; speedup 1.0000x reference)
//
#include <hip/hip_runtime.h>
#include <hip/hip_cooperative_groups.h>

namespace cg = cooperative_groups;

#define V 32
#define B 128
#define P 256
#define J 75
#define NF 32
#define S2 25

// ---------------------------------------------------------------------------
// Kernel 1: transform + SLayer with mask compaction. (unchanged, verified)
// ---------------------------------------------------------------------------
__global__ __launch_bounds__(128) void slayer_kernel(
    const float* __restrict__ births,
    const float* __restrict__ lifetimes,
    const int* __restrict__ mask,
    const float* __restrict__ centers,
    const float* __restrict__ sharpness,
    float* __restrict__ z)                     // [V*B, J]
{
    const int vb = blockIdx.x;                 // v*B + b
    const int v  = vb >> 7;                    // / 128
    const int tid = threadIdx.x;
    const int lane = tid & 63;

    __shared__ float4 pts[P];
    __shared__ int cnt;

    if (tid == 0) cnt = 0;
    __syncthreads();

    const float inv = 0.70710678118654752f;
    #pragma unroll
    for (int c = 0; c < 2; ++c) {
        const int p  = tid + c * 128;
        const int gi = vb * P + p;
        float b0 = births[gi];
        float l0 = lifetimes[gi];
        int   m  = mask[gi];
        float d  = b0 + l0 + 0.01f;
        float x  = (b0 + d) * inv;
        float y  = (d - b0) * inv;
        if (y <= 0.1f) y = __logf(y * 10.0f) * 0.1f + 0.1f;

        bool keep = (m != 0);
        unsigned long long bal = __ballot(keep);
        unsigned long long lt  = (1ull << lane) - 1ull;
        int prefix = __popcll(bal & lt);
        int total  = __popcll(bal);
        int base = 0;
        if (lane == 0) base = atomicAdd(&cnt, total);
        base = __shfl(base, 0, 64);
        if (keep) pts[base + prefix] = make_float4(x, y, x * x, y * y);
    }
    __syncthreads();

    const int n = cnt;
    if (tid < J) {
        const int cj = (v * J + tid) * 2;
        float cx = centers[cj + 0];
        float cy = centers[cj + 1];
        float sx = sharpness[cj + 0];
        float sy = sharpness[cj + 1];
        float s2x = sx * sx, s2y = sy * sy;
        float k0 = -s2x;
        float k1 = -s2y;
        float k2 = 2.0f * s2x * cx;
        float k3 = 2.0f * s2y * cy;
        float kc = -(s2x * cx * cx + s2y * cy * cy);
        float acc = 0.f;
        #pragma unroll 4
        for (int p = 0; p < n; ++p) {
            float4 a = pts[p];
            float d = fmaf(k0, a.z, kc);
            d = fmaf(k1, a.w, d);
            d = fmaf(k2, a.x, d);
            d = fmaf(k3, a.y, d);
            acc += __expf(d);
        }
        z[vb * J + tid] = acc;
    }
}

// ---------------------------------------------------------------------------
// Kernel 2 (fused): stage12 + bn1/l2 + fc1/bn2 + fc2 in ONE cooperative
// kernel with grid.sync() between stages.  256 blocks x 256 threads =
// 1 block/CU, guaranteed co-resident.
//
// Stage A: block bb owns v = bb>>3, batch slice of 16.  Weights (w1, w2,
//          l1_w) staged to LDS ONCE per block (vs once per (v,b) before).
//          3 batch items processed per pass: 225/256 lanes active.
// Stage B: blocks 0..31 = per-v BN(batch) + l2 + ReLU, write xT transposed.
// Stage C: blocks 0..249, 2 fc1 neurons each + BN over batch.
// Stage D: blocks 0..99, 2 fc2 neurons each.
// ---------------------------------------------------------------------------
__global__ __launch_bounds__(256, 1) void fused_rest_kernel(
    const float* __restrict__ z,               // [V*B, J]
    const float* __restrict__ w1,              // [V, NF, 3]
    const float* __restrict__ w2,              // [V, 8, NF]
    const float* __restrict__ l1_w,            // [V, S2, J]
    const float* __restrict__ l1_b,            // [V, S2]
    const float* __restrict__ bn1_g,
    const float* __restrict__ bn1_b,
    const float* __restrict__ l2_w,            // [V, S2, S2]
    const float* __restrict__ l2_b,            // [V, S2]
    const float* __restrict__ fc1_w,           // [500, 800]
    const float* __restrict__ fc1_b,           // [500]
    const float* __restrict__ bn2_g,
    const float* __restrict__ bn2_b,
    const float* __restrict__ fc2_w,           // [200, 500]
    const float* __restrict__ fc2_b,           // [200]
    float* __restrict__ u_pre,                 // [V*B, S2]
    float* __restrict__ xT,                    // [V*S2, B]
    float* __restrict__ y1n,                   // [500, B]
    float* __restrict__ out)                   // [B, 200]
{
    const int bb  = blockIdx.x;
    const int tid = threadIdx.x;
    cg::grid_group grid = cg::this_grid();

    __shared__ float w1s[NF * 3];
    __shared__ float w2s[8 * NF];
    __shared__ float l1ws[S2 * J];
    __shared__ float l1bs[S2];
    __shared__ float zsh[3][3 * J];
    __shared__ float hshA[3 * J];
    __shared__ float ub[B * S2];
    __shared__ float wb[S2 * S2];
    __shared__ float scb[S2], shb[S2];
    __shared__ float wc[2][V * S2];
    __shared__ float redc[4][2];
    __shared__ float wd[2 * 500];

    // ---------------- Stage A: neighbor stack + conv1/conv2/max + l1 -------
    {
        const int v  = bb >> 3;
        const int b0 = (bb & 7) * 16;
        const int vm = (v + V - 1) & (V - 1);
        const int vp = (v + 1) & (V - 1);

        if (tid < NF * 3) w1s[tid] = w1[v * NF * 3 + tid];
        if (tid < 8 * NF) w2s[tid] = w2[v * 8 * NF + tid];
        for (int i = tid; i < S2 * J; i += 256) l1ws[i] = l1_w[v * S2 * J + i];
        if (tid < S2) l1bs[tid] = l1_b[v * S2 + tid];
        __syncthreads();

        for (int bi = 0; bi < 16; bi += 3) {
            const int nb = min(3, 16 - bi);
            // load z rows for nb batch items x {v-1, v, v+1}
            for (int i = tid; i < nb * 3 * J; i += 256) {
                int bl    = i / (3 * J);
                int r     = i - bl * (3 * J);
                int which = r / J;
                int j     = r - which * J;
                int b     = b0 + bi + bl;
                int vsrc  = (which == 0) ? vm : ((which == 1) ? v : vp);
                zsh[bl][which * J + j] = z[(vsrc * B + b) * J + j];
            }
            __syncthreads();

            if (tid < nb * J) {
                int bl = tid / J;
                int j  = tid - bl * J;
                float a0 = zsh[bl][0 * J + j];
                float a1 = zsh[bl][1 * J + j];
                float a2 = zsh[bl][2 * J + j];
                float hf[NF];
                #pragma unroll
                for (int f = 0; f < NF; ++f)
                    hf[f] = w1s[f * 3 + 0] * a0 + w1s[f * 3 + 1] * a1 + w1s[f * 3 + 2] * a2;
                float hm = -3.4e38f;
                #pragma unroll
                for (int g = 0; g < 8; ++g) {
                    float s = 0.f;
                    #pragma unroll
                    for (int f = 0; f < NF; ++f) s += w2s[g * NF + f] * hf[f];
                    hm = fmaxf(hm, s);
                }
                hshA[bl * J + j] = hm;
            }
            __syncthreads();

            if (tid < nb * S2) {
                int bl = tid / S2;
                int o  = tid - bl * S2;
                float acc = l1bs[o];
                for (int j = 0; j < J; ++j) acc += hshA[bl * J + j] * l1ws[o * J + j];
                u_pre[(v * B + b0 + bi + bl) * S2 + o] = acc;
            }
            __syncthreads();
        }
    }

    grid.sync();

    // ---------------- Stage B: bn1 (batch axis) + l2 + ReLU -> xT ----------
    if (bb < V) {
        const int v = bb;
        for (int i = tid; i < B * S2; i += 256) ub[i] = u_pre[v * B * S2 + i];
        for (int i = tid; i < S2 * S2; i += 256) wb[i] = l2_w[v * S2 * S2 + i];
        __syncthreads();

        if (tid < S2) {
            float s = 0.f, ss = 0.f;
            for (int b = 0; b < B; ++b) {
                float x = ub[b * S2 + tid];
                s += x; ss += x * x;
            }
            float mean = s * (1.f / B);
            float var  = ss * (1.f / B) - mean * mean;
            float istd = rsqrtf(var + 1e-5f);
            float g  = bn1_g[v * S2 + tid];
            float be = bn1_b[v * S2 + tid];
            scb[tid] = g * istd;
            shb[tid] = be - mean * g * istd;
        }
        __syncthreads();

        for (int i = tid; i < B * S2; i += 256) {
            int o = i % S2;
            ub[i] = ub[i] * scb[o] + shb[o];
        }
        __syncthreads();

        for (int i = tid; i < B * S2; i += 256) {
            int b = i & 127;
            int p = i >> 7;
            float acc = l2_b[v * S2 + p];
            #pragma unroll
            for (int o = 0; o < S2; ++o) acc += ub[b * S2 + o] * wb[p * S2 + o];
            acc = fmaxf(acc, 0.f);
            xT[(v * S2 + p) * B + b] = acc;
        }
    }

    grid.sync();

    // ---------------- Stage C: fc1 + bn2 (2 neurons per block) -------------
    if (bb < 250) {
        const int n0 = bb * 2;
        const int K  = V * S2;                 // 800
        for (int i = tid; i < 2 * K; i += 256) {
            int ni = i / K;
            int k  = i - ni * K;
            wc[ni][k] = fc1_w[(n0 + ni) * K + k];
        }
        __syncthreads();

        const int ni = tid >> 7;               // 0/1: which neuron
        const int b  = tid & 127;              // batch index
        float acc = 0.f;
        for (int k = 0; k < K; ++k) acc += xT[k * B + b] * wc[ni][k];
        acc += fc1_b[n0 + ni];

        const int wave = tid >> 6;             // 0..3
        const int lane = tid & 63;
        float s = acc, ss = acc * acc;
        #pragma unroll
        for (int off = 32; off > 0; off >>= 1) {
            s  += __shfl_down(s,  off, 64);
            ss += __shfl_down(ss, off, 64);
        }
        if (lane == 0) { redc[wave][0] = s; redc[wave][1] = ss; }
        __syncthreads();

        float sT  = redc[2 * ni][0] + redc[2 * ni + 1][0];
        float ssT = redc[2 * ni][1] + redc[2 * ni + 1][1];
        float mean = sT * (1.f / B);
        float var  = ssT * (1.f / B) - mean * mean;
        float istd = rsqrtf(var + 1e-5f);
        float g   = bn2_g[n0 + ni];
        float be  = bn2_b[n0 + ni];
        float scl = g * istd;
        y1n[(n0 + ni) * B + b] = acc * scl + (be - mean * scl);
    }

    grid.sync();

    // ---------------- Stage D: fc2 (2 neurons per block) -------------------
    if (bb < 100) {
        for (int i = tid; i < 2 * 500; i += 256) wd[i] = fc2_w[bb * 2 * 500 + i];
        __syncthreads();

        const int ni = tid >> 7;
        const int b  = tid & 127;
        const int k  = bb * 2 + ni;
        float acc = fc2_b[k];
        for (int n = 0; n < 500; ++n) acc += y1n[n * B + b] * wd[ni * 500 + n];
        out[b * 200 + k] = acc;
    }
}

// ---------------------------------------------------------------------------
extern "C" void kernel_launch(void* const* d_in, const int* in_sizes, int n_in,
                              void* d_out, int out_size, void* d_ws, size_t ws_size,
                              hipStream_t stream) {
    const float* births    = (const float*)d_in[0];
    const float* lifetimes = (const float*)d_in[1];
    const int*   mask      = (const int*)d_in[2];
    const float* centers   = (const float*)d_in[3];
    const float* sharpness = (const float*)d_in[4];
    const float* w1        = (const float*)d_in[5];
    const float* w2        = (const float*)d_in[6];
    const float* l1_w      = (const float*)d_in[7];
    const float* l1_b      = (const float*)d_in[8];
    const float* bn1_g     = (const float*)d_in[9];
    const float* bn1_b     = (const float*)d_in[10];
    const float* l2_w      = (const float*)d_in[11];
    const float* l2_b      = (const float*)d_in[12];
    const float* fc1_w     = (const float*)d_in[13];
    const float* fc1_b     = (const float*)d_in[14];
    const float* bn2_g     = (const float*)d_in[15];
    const float* bn2_b     = (const float*)d_in[16];
    const float* fc2_w     = (const float*)d_in[17];
    const float* fc2_b     = (const float*)d_in[18];
    float* out = (float*)d_out;

    float* ws    = (float*)d_ws;
    float* z     = ws;                            // V*B*J   = 307200
    float* u_pre = ws + 307200;                   // V*B*S2  = 102400
    float* xT    = ws + 307200 + 102400;          // 800*B   = 102400
    float* y1n   = ws + 307200 + 102400 + 102400; // 500*B   = 64000

    slayer_kernel<<<V * B, 128, 0, stream>>>(births, lifetimes, mask, centers, sharpness, z);

    void* args[] = {
        (void*)&z, (void*)&w1, (void*)&w2, (void*)&l1_w, (void*)&l1_b,
        (void*)&bn1_g, (void*)&bn1_b, (void*)&l2_w, (void*)&l2_b,
        (void*)&fc1_w, (void*)&fc1_b, (void*)&bn2_g, (void*)&bn2_b,
        (void*)&fc2_w, (void*)&fc2_b,
        (void*)&u_pre, (void*)&xT, (void*)&y1n, (void*)&out
    };
    hipLaunchCooperativeKernel((const void*)fused_rest_kernel,
                               dim3(256), dim3(256), args, 0, stream);
}

// Round 3
// 152.975 us; speedup vs baseline: 3.9213x; 3.9213x over previous
//
#include <hip/hip_runtime.h>

#define V 32
#define B 128
#define P 256
#define J 75
#define NF 32
#define S2 25

// ---------------------------------------------------------------------------
// Kernel 1: transform + SLayer with mask compaction.
// 256 threads: phase 1 = one point per thread; phase 2 = 3-way split of the
// point loop (thread = part*75 + j, 225 active lanes), LDS combine.
// ---------------------------------------------------------------------------
__global__ __launch_bounds__(256) void slayer_kernel(
    const float* __restrict__ births,
    const float* __restrict__ lifetimes,
    const int* __restrict__ mask,
    const float* __restrict__ centers,
    const float* __restrict__ sharpness,
    float* __restrict__ z)                     // [V*B, J]
{
    const int vb = blockIdx.x;                 // v*B + b
    const int v  = vb >> 7;                    // / 128
    const int tid = threadIdx.x;
    const int lane = tid & 63;

    __shared__ float4 pts[P];
    __shared__ int cnt;
    __shared__ float part[2][J];

    if (tid == 0) cnt = 0;
    __syncthreads();

    const float inv = 0.70710678118654752f;
    {
        const int gi = vb * P + tid;
        float b0 = births[gi];
        float l0 = lifetimes[gi];
        int   m  = mask[gi];
        float d  = b0 + l0 + 0.01f;
        float x  = (b0 + d) * inv;
        float y  = (d - b0) * inv;
        if (y <= 0.1f) y = __logf(y * 10.0f) * 0.1f + 0.1f;

        bool keep = (m != 0);
        unsigned long long bal = __ballot(keep);
        unsigned long long lt  = (1ull << lane) - 1ull;
        int prefix = __popcll(bal & lt);
        int total  = __popcll(bal);
        int base = 0;
        if (lane == 0) base = atomicAdd(&cnt, total);
        base = __shfl(base, 0, 64);
        if (keep) pts[base + prefix] = make_float4(x, y, x * x, y * y);
    }
    __syncthreads();

    const int n = cnt;
    float acc = 0.f;
    if (tid < 3 * J) {
        const int pid = tid / J;               // 0,1,2
        const int j   = tid - pid * J;
        const int cj  = (v * J + j) * 2;
        float cx = centers[cj + 0];
        float cy = centers[cj + 1];
        float sx = sharpness[cj + 0];
        float sy = sharpness[cj + 1];
        float s2x = sx * sx, s2y = sy * sy;
        // pre-negated coefficients: argument to exp is already -d2
        float k0 = -s2x;
        float k1 = -s2y;
        float k2 = 2.0f * s2x * cx;
        float k3 = 2.0f * s2y * cy;
        float kc = -(s2x * cx * cx + s2y * cy * cy);
        const int p0 = (n * pid) / 3;
        const int p1 = (n * (pid + 1)) / 3;
        #pragma unroll 4
        for (int p = p0; p < p1; ++p) {
            float4 a = pts[p];
            float d = fmaf(k0, a.z, kc);
            d = fmaf(k1, a.w, d);
            d = fmaf(k2, a.x, d);
            d = fmaf(k3, a.y, d);
            acc += __expf(d);
        }
        if (pid > 0) part[pid - 1][j] = acc;
    }
    __syncthreads();

    if (tid < J)
        z[vb * J + tid] = acc + part[0][tid] + part[1][tid];
}

// ---------------------------------------------------------------------------
// Kernel 2: neighbor stack + stage_1 + l1.  3 batch items per block,
// 256 threads; weights staged once per block.  grid = V * 43.
// ---------------------------------------------------------------------------
#define BCH 43                                  // ceil(128/3)
__global__ __launch_bounds__(256) void stage12_kernel(
    const float* __restrict__ z,               // [V*B, J]
    const float* __restrict__ w1,              // [V, NF, 3]
    const float* __restrict__ w2,              // [V, 8, NF]
    const float* __restrict__ l1_w,            // [V, S2, J]
    const float* __restrict__ l1_b,            // [V, S2]
    float* __restrict__ u_pre)                 // [V*B, S2]
{
    const int bb    = blockIdx.x;
    const int v     = bb / BCH;
    const int chunk = bb - v * BCH;
    const int b0    = chunk * 3;
    const int nb    = (b0 + 3 <= B) ? 3 : (B - b0);
    const int vm = (v + V - 1) & (V - 1);
    const int vp = (v + 1) & (V - 1);
    const int tid = threadIdx.x;

    __shared__ float w1s[NF * 3];
    __shared__ float w2s[8 * NF];
    __shared__ float l1ws[S2 * J];
    __shared__ float l1bs[S2];
    __shared__ float zsh[3][3 * J];
    __shared__ float hshA[3 * J];
    __shared__ float lred[3][J];               // 25 o x 3 kk per batch item

    if (tid < NF * 3) w1s[tid] = w1[v * NF * 3 + tid];
    if (tid < 8 * NF) w2s[tid] = w2[v * 8 * NF + tid];
    for (int i = tid; i < S2 * J; i += 256) l1ws[i] = l1_w[v * S2 * J + i];
    if (tid < S2) l1bs[tid] = l1_b[v * S2 + tid];

    for (int i = tid; i < nb * 3 * J; i += 256) {
        int bl    = i / (3 * J);
        int r     = i - bl * (3 * J);
        int which = r / J;
        int j     = r - which * J;
        int b     = b0 + bl;
        int vsrc  = (which == 0) ? vm : ((which == 1) ? v : vp);
        zsh[bl][which * J + j] = z[(vsrc * B + b) * J + j];
    }
    __syncthreads();

    if (tid < nb * J) {
        int bl = tid / J;
        int j  = tid - bl * J;
        float a0 = zsh[bl][0 * J + j];
        float a1 = zsh[bl][1 * J + j];
        float a2 = zsh[bl][2 * J + j];
        float hf[NF];
        #pragma unroll
        for (int f = 0; f < NF; ++f)
            hf[f] = w1s[f * 3 + 0] * a0 + w1s[f * 3 + 1] * a1 + w1s[f * 3 + 2] * a2;
        float hm = -3.4e38f;
        #pragma unroll
        for (int g = 0; g < 8; ++g) {
            float s = 0.f;
            #pragma unroll
            for (int f = 0; f < NF; ++f) s += w2s[g * NF + f] * hf[f];
            hm = fmaxf(hm, s);
        }
        hshA[bl * J + j] = hm;
    }
    __syncthreads();

    // l1: thread = (bl, o, kk): o in 25, kk in 3 chunks of 25 j's
    if (tid < nb * J) {
        int bl = tid / J;
        int r  = tid - bl * J;
        int o  = r / 3;
        int kk = r - o * 3;
        const float* wrow = l1ws + o * J + kk * 25;
        const float* hrow = hshA + bl * J + kk * 25;
        float acc = 0.f;
        #pragma unroll
        for (int j = 0; j < 25; ++j) acc += hrow[j] * wrow[j];
        lred[bl][r] = acc;
    }
    __syncthreads();

    if (tid < nb * S2) {
        int bl = tid / S2;
        int o  = tid - bl * S2;
        float acc = l1bs[o] + lred[bl][o * 3 + 0] + lred[bl][o * 3 + 1] + lred[bl][o * 3 + 2];
        u_pre[(v * B + b0 + bl) * S2 + o] = acc;
    }
}

// ---------------------------------------------------------------------------
// Kernel 3: BN over batch axis (per v,o) + l2 + ReLU.  One block per v.
// BN stats reduced by 200 threads (8 chunks x 25 outputs).
// ---------------------------------------------------------------------------
__global__ __launch_bounds__(256) void bn1_l2_kernel(
    const float* __restrict__ u_pre,           // [V*B, S2]
    const float* __restrict__ bn1_g,
    const float* __restrict__ bn1_b,
    const float* __restrict__ l2_w,            // [V, S2, S2]
    const float* __restrict__ l2_b,            // [V, S2]
    float* __restrict__ xT)                    // [V*S2, B]
{
    const int v = blockIdx.x;
    const int tid = threadIdx.x;

    __shared__ float u[B * S2];
    __shared__ float w[S2 * S2];
    __shared__ float sred[8 * S2], ssred[8 * S2];
    __shared__ float sc[S2], sh[S2];

    for (int i = tid; i < B * S2; i += 256) u[i] = u_pre[v * B * S2 + i];
    for (int i = tid; i < S2 * S2; i += 256) w[i] = l2_w[v * S2 * S2 + i];
    __syncthreads();

    if (tid < 8 * S2) {
        int c = tid / S2;
        int o = tid - c * S2;
        float s = 0.f, ss = 0.f;
        #pragma unroll
        for (int b = c * 16; b < c * 16 + 16; ++b) {
            float x = u[b * S2 + o];
            s += x; ss += x * x;
        }
        sred[tid] = s; ssred[tid] = ss;
    }
    __syncthreads();

    if (tid < S2) {
        float s = 0.f, ss = 0.f;
        #pragma unroll
        for (int c = 0; c < 8; ++c) { s += sred[c * S2 + tid]; ss += ssred[c * S2 + tid]; }
        float mean = s * (1.f / B);
        float var  = ss * (1.f / B) - mean * mean;
        float istd = rsqrtf(var + 1e-5f);
        float g  = bn1_g[v * S2 + tid];
        float be = bn1_b[v * S2 + tid];
        sc[tid] = g * istd;
        sh[tid] = be - mean * g * istd;
    }
    __syncthreads();

    for (int i = tid; i < B * S2; i += 256) {
        int o = i % S2;
        u[i] = u[i] * sc[o] + sh[o];
    }
    __syncthreads();

    for (int i = tid; i < B * S2; i += 256) {
        int b = i & 127;
        int p = i >> 7;
        float acc = l2_b[v * S2 + p];
        #pragma unroll
        for (int o = 0; o < S2; ++o) acc += u[b * S2 + o] * w[p * S2 + o];
        acc = fmaxf(acc, 0.f);
        xT[(v * S2 + p) * B + b] = acc;
    }
}

// ---------------------------------------------------------------------------
// Kernel 4: fc1 + BN over batch.  One block per neuron (500 blocks),
// 256 threads: K=800 split into two 400-iter halves (kk = tid>>7).
// ---------------------------------------------------------------------------
__global__ __launch_bounds__(256) void fc1_bn2_kernel(
    const float* __restrict__ xT,              // [800, B]
    const float* __restrict__ fc1_w,           // [500, 800]
    const float* __restrict__ fc1_b,           // [500]
    const float* __restrict__ bn2_g,
    const float* __restrict__ bn2_b,
    float* __restrict__ y1n)                   // [500, B]
{
    const int n  = blockIdx.x;                 // neuron
    const int tid = threadIdx.x;
    const int kk = tid >> 7;                   // 0/1: K half
    const int b  = tid & 127;
    const int K  = V * S2;                     // 800

    __shared__ float wsm[V * S2];
    __shared__ float pr[B];
    __shared__ float red[2][2];

    for (int i = tid; i < K; i += 256) wsm[i] = fc1_w[n * K + i];
    __syncthreads();

    float acc = 0.f;
    const float* xp = xT + kk * 400 * B + b;
    const float* wp = wsm + kk * 400;
    for (int k = 0; k < 400; ++k) acc += xp[k * B] * wp[k];

    if (kk == 1) pr[b] = acc;
    __syncthreads();

    float t = 0.f;
    if (kk == 0) {
        t = acc + pr[b] + fc1_b[n];
        const int wave = tid >> 6;             // 0/1
        const int lane = tid & 63;
        float s = t, ss = t * t;
        #pragma unroll
        for (int off = 32; off > 0; off >>= 1) {
            s  += __shfl_down(s,  off, 64);
            ss += __shfl_down(ss, off, 64);
        }
        if (lane == 0) { red[wave][0] = s; red[wave][1] = ss; }
    }
    __syncthreads();

    if (kk == 0) {
        float s  = red[0][0] + red[1][0];
        float ss = red[0][1] + red[1][1];
        float mean = s * (1.f / B);
        float var  = ss * (1.f / B) - mean * mean;
        float istd = rsqrtf(var + 1e-5f);
        float g   = bn2_g[n];
        float be  = bn2_b[n];
        float scl = g * istd;
        y1n[n * B + b] = t * scl + (be - mean * scl);
    }
}

// ---------------------------------------------------------------------------
// Kernel 5: fc2.  One block per output neuron (200), 256 threads:
// K=500 split into two 250-iter halves.
// ---------------------------------------------------------------------------
__global__ __launch_bounds__(256) void fc2_kernel(
    const float* __restrict__ y1n,             // [500, B]
    const float* __restrict__ fc2_w,           // [200, 500]
    const float* __restrict__ fc2_b,           // [200]
    float* __restrict__ out)                   // [B, 200]
{
    const int n2 = blockIdx.x;
    const int tid = threadIdx.x;
    const int kk = tid >> 7;
    const int b  = tid & 127;

    __shared__ float wsm[500];
    __shared__ float pr[B];
    for (int i = tid; i < 500; i += 256) wsm[i] = fc2_w[n2 * 500 + i];
    __syncthreads();

    float acc = 0.f;
    const float* yp = y1n + kk * 250 * B + b;
    const float* wp = wsm + kk * 250;
    for (int k = 0; k < 250; ++k) acc += yp[k * B] * wp[k];

    if (kk == 1) pr[b] = acc;
    __syncthreads();

    if (kk == 0)
        out[b * 200 + n2] = acc + pr[b] + fc2_b[n2];
}

// ---------------------------------------------------------------------------
extern "C" void kernel_launch(void* const* d_in, const int* in_sizes, int n_in,
                              void* d_out, int out_size, void* d_ws, size_t ws_size,
                              hipStream_t stream) {
    const float* births    = (const float*)d_in[0];
    const float* lifetimes = (const float*)d_in[1];
    const int*   mask      = (const int*)d_in[2];
    const float* centers   = (const float*)d_in[3];
    const float* sharpness = (const float*)d_in[4];
    const float* w1        = (const float*)d_in[5];
    const float* w2        = (const float*)d_in[6];
    const float* l1_w      = (const float*)d_in[7];
    const float* l1_b      = (const float*)d_in[8];
    const float* bn1_g     = (const float*)d_in[9];
    const float* bn1_b     = (const float*)d_in[10];
    const float* l2_w      = (const float*)d_in[11];
    const float* l2_b      = (const float*)d_in[12];
    const float* fc1_w     = (const float*)d_in[13];
    const float* fc1_b     = (const float*)d_in[14];
    const float* bn2_g     = (const float*)d_in[15];
    const float* bn2_b     = (const float*)d_in[16];
    const float* fc2_w     = (const float*)d_in[17];
    const float* fc2_b     = (const float*)d_in[18];
    float* out = (float*)d_out;

    float* ws    = (float*)d_ws;
    float* z     = ws;                            // V*B*J   = 307200
    float* u_pre = ws + 307200;                   // V*B*S2  = 102400
    float* xT    = ws + 307200 + 102400;          // 800*B   = 102400
    float* y1n   = ws + 307200 + 102400 + 102400; // 500*B   = 64000

    slayer_kernel <<<V * B, 256, 0, stream>>>(births, lifetimes, mask, centers, sharpness, z);
    stage12_kernel<<<V * BCH, 256, 0, stream>>>(z, w1, w2, l1_w, l1_b, u_pre);
    bn1_l2_kernel <<<V, 256, 0, stream>>>(u_pre, bn1_g, bn1_b, l2_w, l2_b, xT);
    fc1_bn2_kernel<<<500, 256, 0, stream>>>(xT, fc1_w, fc1_b, bn2_g, bn2_b, y1n);
    fc2_kernel    <<<200, 256, 0, stream>>>(y1n, fc2_w, fc2_b, out);
}